// Round 2
// baseline (74.200 us; speedup 1.0000x reference)
//
#include <hip/hip_runtime.h>
#include <math.h>

#define GLCM_L   16
#define IMG_H    512
#define IMG_W    512
#define N_IMG    128
#define STRIPS   8
#define ROWS_PER_STRIP (IMG_H / STRIPS)   // 64
#define NBINS    256                      // GLCM_L * GLCM_L

// ---------------------------------------------------------------------------
// Kernel 1: per-image 256-bin joint histogram over 4 angles (wraparound roll).
// Pairs per pixel (i,j), q = quantized image:
//   angle   0: (q[i][j], q[i][(j-1)%W])       -> left
//   angle  45: (q[i][j], q[(i-1)%H][(j+1)%W]) -> up-right
//   angle  90: (q[i][j], q[(i-1)%H][j])       -> up
//   angle 135: (q[i][j], q[(i-1)%H][(j-1)%W]) -> up-left
// Grid: (STRIPS, N_IMG). 256 threads, 4 per-wave LDS histograms.
// ---------------------------------------------------------------------------
__global__ __launch_bounds__(256) void glcm_hist_kernel(
    const float* __restrict__ x, unsigned int* __restrict__ hist) {

    __shared__ unsigned int lh[4][NBINS];
    const int tid  = threadIdx.x;
    const int wave = tid >> 6;
    const int img  = blockIdx.y;
    const int strip = blockIdx.x;

    for (int i = tid; i < 4 * NBINS; i += 256) ((unsigned int*)lh)[i] = 0u;
    __syncthreads();

    const float* __restrict__ base = x + (size_t)img * (IMG_H * IMG_W);
    unsigned int* mh = lh[wave];

    // 256 threads cover 2 rows per iteration, 4 pixels per thread.
    const int half = tid >> 7;            // 0/1: which of the two rows
    const int jj   = (tid & 127) << 2;    // column of first pixel [0..508]
    const int jm1  = (jj + IMG_W - 1) & (IMG_W - 1);
    const int jp4  = (jj + 4) & (IMG_W - 1);
    const int rowBase = strip * ROWS_PER_STRIP;

    for (int it = 0; it < ROWS_PER_STRIP / 2; ++it) {
        const int r  = rowBase + it * 2 + half;
        const int ru = (r + IMG_H - 1) & (IMG_H - 1);  // row above (wrap)

        const float4 c4 = *reinterpret_cast<const float4*>(base + (size_t)r  * IMG_W + jj);
        const float4 u4 = *reinterpret_cast<const float4*>(base + (size_t)ru * IMG_W + jj);
        const float  cm1 = base[(size_t)r  * IMG_W + jm1];
        const float  um1 = base[(size_t)ru * IMG_W + jm1];
        const float  up4 = base[(size_t)ru * IMG_W + jp4];

        // quantize: trunc toward zero, matches (img*(L-1)).astype(int32)
        int qc[5];  // qc[0] = left-of-first, qc[1..4] = the 4 pixels
        int qu[6];  // qu[0] = up-left-of-first, qu[1..4] = up row, qu[5] = up-right-of-last
        qc[0] = (int)(cm1 * 15.0f);
        qc[1] = (int)(c4.x * 15.0f); qc[2] = (int)(c4.y * 15.0f);
        qc[3] = (int)(c4.z * 15.0f); qc[4] = (int)(c4.w * 15.0f);
        qu[0] = (int)(um1 * 15.0f);
        qu[1] = (int)(u4.x * 15.0f); qu[2] = (int)(u4.y * 15.0f);
        qu[3] = (int)(u4.z * 15.0f); qu[4] = (int)(u4.w * 15.0f);
        qu[5] = (int)(up4 * 15.0f);

        #pragma unroll
        for (int k = 0; k < 4; ++k) {
            const int q = qc[k + 1] << 4;
            atomicAdd(&mh[q + qc[k]],     1u);  // angle   0 (left)
            atomicAdd(&mh[q + qu[k + 2]], 1u);  // angle  45 (up-right)
            atomicAdd(&mh[q + qu[k + 1]], 1u);  // angle  90 (up)
            atomicAdd(&mh[q + qu[k]],     1u);  // angle 135 (up-left)
        }
    }

    __syncthreads();
    // tid == bin index; merge 4 wave-private copies, one global atomic per bin
    const unsigned int total = lh[0][tid] + lh[1][tid] + lh[2][tid] + lh[3][tid];
    atomicAdd(&hist[img * NBINS + tid], total);
}

// ---------------------------------------------------------------------------
// Kernel 2: entropy of each image's normalized histogram. 128 blocks.
// counts.sum() == 4*H*W == 2^20 exactly.
// ---------------------------------------------------------------------------
__global__ __launch_bounds__(256) void glcm_entropy_kernel(
    const unsigned int* __restrict__ hist, float* __restrict__ ent) {

    __shared__ float partial[4];
    const int img = blockIdx.x;
    const int tid = threadIdx.x;

    const float c = (float)hist[img * NBINS + tid];
    const float p = c * (1.0f / 1048576.0f);   // exact (power-of-2 scale)
    float t = p * logf(p + 1e-10f);

    #pragma unroll
    for (int off = 32; off > 0; off >>= 1) t += __shfl_down(t, off, 64);
    if ((tid & 63) == 0) partial[tid >> 6] = t;
    __syncthreads();
    if (tid == 0) ent[img] = -(partial[0] + partial[1] + partial[2] + partial[3]);
}

// ---------------------------------------------------------------------------
// Kernel 3: broadcast each scalar to its (H,W) slice. float4 stores.
// 65536 float4 per image -> img = v >> 16.
// ---------------------------------------------------------------------------
__global__ __launch_bounds__(256) void glcm_fill_kernel(
    const float* __restrict__ ent, float4* __restrict__ out) {

    const int n4 = N_IMG * IMG_H * IMG_W / 4;  // 8388608
    const int stride = gridDim.x * 256;
    for (int v = blockIdx.x * 256 + threadIdx.x; v < n4; v += stride) {
        const float e = ent[v >> 16];
        out[v] = make_float4(e, e, e, e);
    }
}

extern "C" void kernel_launch(void* const* d_in, const int* in_sizes, int n_in,
                              void* d_out, int out_size, void* d_ws, size_t ws_size,
                              hipStream_t stream) {
    const float* x = (const float*)d_in[0];
    float4* out4 = reinterpret_cast<float4*>(d_out);

    unsigned int* hist = (unsigned int*)d_ws;
    float* ent = (float*)((char*)d_ws + (size_t)N_IMG * NBINS * sizeof(unsigned int));

    // histograms must start at zero every call (harness does not re-poison)
    (void)hipMemsetAsync(d_ws, 0, (size_t)N_IMG * NBINS * sizeof(unsigned int), stream);

    glcm_hist_kernel<<<dim3(STRIPS, N_IMG), 256, 0, stream>>>(x, hist);
    glcm_entropy_kernel<<<N_IMG, 256, 0, stream>>>(hist, ent);
    glcm_fill_kernel<<<2048, 256, 0, stream>>>(ent, out4);
}